// Round 5
// baseline (723.671 us; speedup 1.0000x reference)
//
#include <hip/hip_runtime.h>
#include <hip/hip_bf16.h>
#include <math.h>

#define S_ 256
#define B_ 16
#define D_ 512
#define V_ 32000
#define L_ 4
#define DEC_ 0.6065306597126334f   // float(exp(-1/2))

typedef short v8s __attribute__((ext_vector_type(8)));
typedef float v4f __attribute__((ext_vector_type(4)));

// ---------------- encoder GEMM + scratch zero-init + cvec (spare blocks) ----------------
// X[s*B+b][n] = emb[ids[b][s]] . enc_W[n][:] + enc_b[n]
// grid (65, 8): bm<64 = gemm tiles; bm==64,bn<4 = cvec for layer j=bn.
__global__ __launch_bounds__(256) void k_gemm_enc(const int* __restrict__ ids,
                                                  const float* __restrict__ emb,
                                                  const float* __restrict__ encW,
                                                  const float* __restrict__ encb,
                                                  float* __restrict__ X,
                                                  unsigned* __restrict__ counts,
                                                  unsigned* __restrict__ bunz,
                                                  float* __restrict__ accum,
                                                  const float* __restrict__ inf_W,
                                                  const float* __restrict__ inf_b,
                                                  const float* __restrict__ err_b,
                                                  float* __restrict__ cvec){
  const int t = threadIdx.x;
  const int bm = blockIdx.x, bn = blockIdx.y;
  if (bm == 64){
    // cvec: c_j = err_b[j] @ inf_W[j]^T + inf_b[j]   (used by k_sim top-down)
    if (bn >= 4) return;
    int j = bn;
    #pragma unroll
    for (int h = 0; h < 2; ++h){
      int dp = t + h*256;
      const float* row = inf_W + ((size_t)j * D_ + dp) * D_;
      const float* eb = err_b + j * D_;
      float acc = inf_b[j * D_ + dp];
      for (int d = 0; d < D_; d += 8){
        float4 w0 = *(const float4*)(row + d);
        float4 w1 = *(const float4*)(row + d + 4);
        float4 e0 = *(const float4*)(eb + d);
        float4 e1 = *(const float4*)(eb + d + 4);
        acc += e0.x*w0.x + e0.y*w0.y + e0.z*w0.z + e0.w*w0.w;
        acc += e1.x*w1.x + e1.y*w1.y + e1.z*w1.z + e1.w*w1.w;
      }
      cvec[j * D_ + dp] = acc;
    }
    return;
  }
  __shared__ __align__(16) short As[64*40];
  __shared__ __align__(16) short Bs[64*40];
  __shared__ int ids_s[64];
  // zero-init scratch (k_scan/k_sim run after this kernel completes)
  if (bn == 0 && bm < 16){
    int g = bm*256 + t;
    counts[g] = 0u;
    bunz[g] = 0u;
    if (g < 2) accum[g] = 0.0f;
  }
  if (t < 64){
    int mg = bm*64 + t;
    int s = mg >> 4, b = mg & 15;       // row r = s*B + b
    ids_s[t] = ids[b * S_ + s];
  }
  __syncthreads();
  const int arow = t >> 2;
  const int kc = (t & 3) * 8;
  const int wave = t >> 6;
  const int l = t & 63;
  const int lm = l & 15;
  const int q = l >> 4;
  v4f acc[4] = {};
  for (int k0 = 0; k0 < D_; k0 += 32){
    const float* asrc = emb + (size_t)ids_s[arow] * D_ + k0 + kc;
    float4 a0 = *(const float4*)asrc;
    float4 a1 = *(const float4*)(asrc + 4);
    const float* bsrc = encW + (size_t)(bn*64 + arow) * D_ + k0 + kc;
    float4 b0 = *(const float4*)bsrc;
    float4 b1 = *(const float4*)(bsrc + 4);
    union { v8s v; __hip_bfloat162 h[4]; } ua, ub;
    ua.h[0] = __float22bfloat162_rn(make_float2(a0.x, a0.y));
    ua.h[1] = __float22bfloat162_rn(make_float2(a0.z, a0.w));
    ua.h[2] = __float22bfloat162_rn(make_float2(a1.x, a1.y));
    ua.h[3] = __float22bfloat162_rn(make_float2(a1.z, a1.w));
    ub.h[0] = __float22bfloat162_rn(make_float2(b0.x, b0.y));
    ub.h[1] = __float22bfloat162_rn(make_float2(b0.z, b0.w));
    ub.h[2] = __float22bfloat162_rn(make_float2(b1.x, b1.y));
    ub.h[3] = __float22bfloat162_rn(make_float2(b1.z, b1.w));
    *(v8s*)&As[arow*40 + kc] = ua.v;
    *(v8s*)&Bs[arow*40 + kc] = ub.v;
    __syncthreads();
    v8s af = *(const v8s*)&As[(wave*16 + lm)*40 + q*8];
    #pragma unroll
    for (int n = 0; n < 4; ++n){
      v8s bf = *(const v8s*)&Bs[(n*16 + lm)*40 + q*8];
      acc[n] = __builtin_amdgcn_mfma_f32_16x16x32_bf16(af, bf, acc[n], 0, 0, 0);
    }
    __syncthreads();
  }
  // C/D layout: col = lane&15, row = (lane>>4)*4 + reg  [m89/m91 verified]
  #pragma unroll
  for (int n = 0; n < 4; ++n){
    #pragma unroll
    for (int i = 0; i < 4; ++i){
      int mloc = wave*16 + q*4 + i;
      int nloc = n*16 + lm;
      int r  = bm*64 + mloc;
      int nn = bn*64 + nloc;
      X[(size_t)r * D_ + nn] = acc[n][i] + encb[nn];
    }
  }
}

// ---------------- encoder LIF scan: 128 blocks x 64, 16-deep load pipeline ----------------
__global__ __launch_bounds__(64) void k_scan(const float* __restrict__ X,
                                             unsigned char* __restrict__ bu,
                                             unsigned* __restrict__ bunz){
  int g = blockIdx.x * 64 + threadIdx.x;   // g = b*512 + d, 0..8191
  int b = g >> 9;
  float mem = 0.0f;
  for (int s0 = 0; s0 < S_; s0 += 16){
    float x[16];
    #pragma unroll
    for (int i = 0; i < 16; ++i) x[i] = X[(size_t)(s0 + i) * (B_*D_) + g];
    #pragma unroll
    for (int i = 0; i < 16; ++i){
      mem = mem * DEC_ + x[i];
      float sp = (mem >= 1.0f) ? 1.0f : 0.0f;   // atan_spike(mem - 1) == (mem >= 1)
      mem *= (1.0f - sp);
      bu[(size_t)(s0 + i) * (B_*D_) + g] = (unsigned char)sp;
      if (sp != 0.0f) atomicOr(&bunz[(s0 + i) * B_ + b], 1u);
    }
  }
}

// ---------------- main recurrent sim: one wave per batch ----------------
__device__ __forceinline__ float wave_sum(float x){
  #pragma unroll
  for (int o = 32; o > 0; o >>= 1) x += __shfl_xor(x, o);
  return x;
}

__device__ void wave_matvec(const float* __restrict__ W, const float* __restrict__ bias,
                            const float x[8], float y[8], float* xs, int l){
  __syncthreads();
  #pragma unroll
  for (int i = 0; i < 8; ++i) xs[l + 64*i] = x[i];
  __syncthreads();
  #pragma unroll
  for (int i = 0; i < 8; ++i){
    int dp = l + 64*i;
    const float* row = W + (size_t)dp * D_;
    float acc = bias[dp];
    for (int d = 0; d < D_; d += 4){
      float4 w = *(const float4*)(row + d);
      acc += xs[d]*w.x + xs[d+1]*w.y + xs[d+2]*w.z + xs[d+3]*w.w;
    }
    y[i] = acc;
  }
}

__device__ void wave_ln(const float e[8], const float* __restrict__ g,
                        const float* __restrict__ bb, float out[8], int l){
  float s = 0.f;
  #pragma unroll
  for (int i = 0; i < 8; ++i) s += e[i];
  float m = wave_sum(s) * (1.0f/512.0f);
  float s2 = 0.f;
  #pragma unroll
  for (int i = 0; i < 8; ++i){ float d = e[i] - m; s2 += d*d; }
  float var = wave_sum(s2) * (1.0f/512.0f);
  float inv = 1.0f / sqrtf(var + 1e-5f);
  #pragma unroll
  for (int i = 0; i < 8; ++i){
    int d = l + 64*i;
    out[i] = (e[i] - m) * inv * g[d] + bb[d];
  }
}

__global__ __launch_bounds__(64) void k_sim(
    const float* __restrict__ gen_W, const float* __restrict__ gen_b,
    const float* __restrict__ inf_W, const float* __restrict__ inf_b,
    const float* __restrict__ err_g, const float* __restrict__ err_b,
    const float* __restrict__ st_g, const float* __restrict__ st_b,
    const unsigned char* __restrict__ bu8, const unsigned* __restrict__ bunz,
    const float* __restrict__ cvec,
    unsigned* __restrict__ counts, unsigned short* __restrict__ idxb,
    float* __restrict__ accum)
{
  const int b = blockIdx.x, l = threadIdx.x;
  __shared__ float xs[D_];
  __shared__ unsigned scnt;
  float st[4][8], gm[4][8], im[4][8];
  #pragma unroll
  for (int j = 0; j < 4; ++j)
    #pragma unroll
    for (int i = 0; i < 8; ++i){ st[j][i]=0.f; gm[j][i]=0.f; im[j][i]=0.f; }

  bool okz = true;
  #pragma unroll
  for (int j = 0; j < 4; ++j)
    #pragma unroll
    for (int i = 0; i < 8; ++i){
      int d = j*512 + l + 64*i;
      okz = okz && (gen_b[d]==0.f) && (inf_b[d]==0.f) && (err_b[d]==0.f) && (st_b[d]==0.f);
    }
  const bool bias_zero = (__all((int)okz) != 0);

  unsigned long long fl[4];
  #pragma unroll
  for (int w = 0; w < 4; ++w){
    unsigned v = bunz[(w*64 + l) * B_ + b];
    fl[w] = __ballot(v != 0u);
  }

  bool state_zero = true;
  float spk_acc = 0.f, memp_acc = 0.f;

  for (int t = 0; t < S_; ++t){
    bool nz = ((fl[t >> 6] >> (t & 63)) & 1ull) != 0ull;
    if (state_zero && bias_zero && !nz) continue;   // zero fixed point: step is identity, td_t = 0
    state_zero = false;

    float bu[8];
    #pragma unroll
    for (int i = 0; i < 8; ++i) bu[i] = (float)bu8[(size_t)(t*B_ + b)*D_ + l + 64*i];

    // ---- bottom-up ----
    #pragma unroll
    for (int j = 0; j < 4; ++j){
      float y[8];
      wave_matvec(gen_W + (size_t)j*D_*D_, gen_b + j*D_, st[j], y, xs, l);
      float pred[8];
      #pragma unroll
      for (int i = 0; i < 8; ++i){
        gm[j][i] = gm[j][i]*DEC_ + y[i];
        pred[i] = (gm[j][i] >= 1.0f) ? 1.0f : 0.0f;
        gm[j][i] *= (1.0f - pred[i]);
      }
      float e[8];
      #pragma unroll
      for (int i = 0; i < 8; ++i){ float v = bu[i] - pred[i]; e[i] = v > 0.f ? v : 0.f; }
      float eo[8];
      wave_ln(e, err_g + j*D_, err_b + j*D_, eo, l);
      #pragma unroll
      for (int i = 0; i < 8; ++i) spk_acc += eo[i];
      float y2[8];
      wave_matvec(inf_W + (size_t)j*D_*D_, inf_b + j*D_, eo, y2, xs, l);
      float su[8];
      #pragma unroll
      for (int i = 0; i < 8; ++i){
        im[j][i] = im[j][i]*DEC_ + y2[i];
        su[i] = (im[j][i] >= 1.0f) ? 1.0f : 0.0f;
        im[j][i] *= (1.0f - su[i]);
        memp_acc += fabsf(im[j][i]);
      }
      float tmp[8];
      #pragma unroll
      for (int i = 0; i < 8; ++i) tmp[i] = st[j][i] + su[i];
      wave_ln(tmp, st_g + j*D_, st_b + j*D_, st[j], l);
      #pragma unroll
      for (int i = 0; i < 8; ++i) bu[i] = st[j][i] > 0.f ? st[j][i] : 0.f;
    }

    // ---- top-down (err == LN(0) == err_b identically, so inf input is cvec[j]) ----
    float td[8];
    #pragma unroll
    for (int i = 0; i < 8; ++i) td[i] = st[3][i];
    #pragma unroll
    for (int j = 3; j >= 0; --j){
      float y[8];
      wave_matvec(gen_W + (size_t)j*D_*D_, gen_b + j*D_, td, y, xs, l);
      #pragma unroll
      for (int i = 0; i < 8; ++i){
        gm[j][i] = gm[j][i]*DEC_ + y[i];
        float p = (gm[j][i] >= 1.0f) ? 1.0f : 0.0f;
        gm[j][i] *= (1.0f - p);
        td[i] = p;
      }
      #pragma unroll
      for (int i = 0; i < 8; ++i){
        float c = cvec[j*D_ + l + 64*i];
        im[j][i] = im[j][i]*DEC_ + c;
        float ss = (im[j][i] >= 1.0f) ? 1.0f : 0.0f;
        im[j][i] *= (1.0f - ss);
      }
    }

    if (l == 0) scnt = 0u;
    __syncthreads();
    unsigned base = (unsigned)(t*B_ + b) * D_;
    #pragma unroll
    for (int i = 0; i < 8; ++i){
      if (td[i] != 0.f){
        unsigned pos = atomicAdd(&scnt, 1u);
        idxb[base + pos] = (unsigned short)(l + 64*i);
      }
    }
    __syncthreads();
    if (l == 0) counts[t*B_ + b] = scnt;
  }
  spk_acc = wave_sum(spk_acc);
  memp_acc = wave_sum(memp_acc);
  if (l == 0){
    atomicAdd(&accum[0], spk_acc);
    atomicAdd(&accum[1], memp_acc);
  }
}

// ---------------- logits: column-chunk-resident out_b, 2-row NT store streams ----------------
// grid = 25 col-chunks x 128 row-groups; block = 1 wave (64 threads).
__device__ __forceinline__ void logits_general(float* __restrict__ dst, const v4f pay[5],
                                               const unsigned short* __restrict__ idxb,
                                               const float* __restrict__ outW,
                                               int row, int colbase, int lane, unsigned cnt){
  int s = row & 255, b = row >> 8;
  unsigned base = (unsigned)(s * B_ + b) * D_;
  v4f acc[5];
  #pragma unroll
  for (int k = 0; k < 5; ++k) acc[k] = pay[k];
  for (unsigned i = 0; i < cnt; ++i){
    int d = idxb[base + i];
    #pragma unroll
    for (int k = 0; k < 5; ++k){
      int v = colbase + k*256 + lane*4;
      acc[k].x += outW[(size_t)(v+0)*D_ + d];
      acc[k].y += outW[(size_t)(v+1)*D_ + d];
      acc[k].z += outW[(size_t)(v+2)*D_ + d];
      acc[k].w += outW[(size_t)(v+3)*D_ + d];
    }
  }
  #pragma unroll
  for (int k = 0; k < 5; ++k)
    __builtin_nontemporal_store(acc[k], (v4f*)(dst + k*256 + lane*4));
}

__global__ __launch_bounds__(64) void k_logits(const unsigned* __restrict__ counts,
                                               const unsigned short* __restrict__ idxb,
                                               const float* __restrict__ outW,
                                               const float* __restrict__ outb,
                                               const float* __restrict__ accum,
                                               float* __restrict__ out){
  const int chunk = blockIdx.x % 25;
  const int rg = blockIdx.x / 25;
  const int lane = threadIdx.x;
  if (blockIdx.x == 0 && lane == 0){
    const float inv = 1.0f / (float)(B_ * D_ * S_);   // mean over (B,D), then /S
    out[(size_t)B_ * S_ * V_ + 0] = accum[0] * inv;
    out[(size_t)B_ * S_ * V_ + 1] = accum[1] * inv;
  }
  const int colbase = chunk * 1280;
  v4f pay[5];
  #pragma unroll
  for (int k = 0; k < 5; ++k)
    pay[k] = *(const v4f*)(outb + colbase + k*256 + lane*4);

  // prefetch this block's 32 row-counts (lane r holds count for row rg*32+r)
  int prow = rg*32 + (lane & 31);
  unsigned myc = counts[(prow & 255) * B_ + (prow >> 8)];

  for (int r = 0; r < 32; r += 2){
    int row0 = rg*32 + r, row1 = row0 + 1;      // row = b*S + s (output order)
    unsigned c0 = (unsigned)__shfl((int)myc, r);
    unsigned c1 = (unsigned)__shfl((int)myc, r + 1);
    float* dst0 = out + (size_t)row0 * V_ + colbase;
    float* dst1 = out + (size_t)row1 * V_ + colbase;
    if ((c0 | c1) == 0u){
      #pragma unroll
      for (int k = 0; k < 5; ++k){
        __builtin_nontemporal_store(pay[k], (v4f*)(dst0 + k*256 + lane*4));
        __builtin_nontemporal_store(pay[k], (v4f*)(dst1 + k*256 + lane*4));
      }
    } else {
      logits_general(dst0, pay, idxb, outW, row0, colbase, lane, c0);
      logits_general(dst1, pay, idxb, outW, row1, colbase, lane, c1);
    }
  }
}

extern "C" void kernel_launch(void* const* d_in, const int* in_sizes, int n_in,
                              void* d_out, int out_size, void* d_ws, size_t ws_size,
                              hipStream_t stream){
  (void)in_sizes; (void)n_in; (void)out_size; (void)ws_size;
  const int*   input_ids = (const int*)d_in[0];
  const float* embedding = (const float*)d_in[1];
  const float* enc_W = (const float*)d_in[2];
  const float* enc_b = (const float*)d_in[3];
  const float* gen_W = (const float*)d_in[4];
  const float* gen_b = (const float*)d_in[5];
  const float* inf_W = (const float*)d_in[6];
  const float* inf_b = (const float*)d_in[7];
  const float* err_g = (const float*)d_in[8];
  const float* err_b = (const float*)d_in[9];
  const float* st_g  = (const float*)d_in[10];
  const float* st_b  = (const float*)d_in[11];
  const float* out_W = (const float*)d_in[12];
  const float* out_b = (const float*)d_in[13];
  float* out = (float*)d_out;
  char* ws = (char*)d_ws;

  float*          X      = (float*)(ws + 0);                 // 4096*512*4 = 8388608
  unsigned char*  bu     = (unsigned char*)(ws + 8388608);   // 4096*512   = 2097152
  unsigned short* idxb   = (unsigned short*)(ws + 10485760); // 4096*512*2 = 4194304
  unsigned*       counts = (unsigned*)(ws + 14680064);       // 4096*4
  unsigned*       bunz   = (unsigned*)(ws + 14696448);       // 4096*4
  float*          cvec   = (float*)(ws + 14712832);          // 4*512*4
  float*          accum  = (float*)(ws + 14721024);          // 2*4

  hipLaunchKernelGGL(k_gemm_enc, dim3(65, 8), dim3(256), 0, stream,
                     input_ids, embedding, enc_W, enc_b, X, counts, bunz, accum,
                     inf_W, inf_b, err_b, cvec);
  hipLaunchKernelGGL(k_scan, dim3(128), dim3(64), 0, stream, X, bu, bunz);
  hipLaunchKernelGGL(k_sim, dim3(16), dim3(64), 0, stream,
                     gen_W, gen_b, inf_W, inf_b, err_g, err_b, st_g, st_b,
                     bu, bunz, cvec, counts, idxb, accum);
  hipLaunchKernelGGL(k_logits, dim3(3200), dim3(64), 0, stream,
                     counts, idxb, out_W, out_b, accum, out);
}

// Round 6
// 708.021 us; speedup vs baseline: 1.0221x; 1.0221x over previous
//
#include <hip/hip_runtime.h>
#include <hip/hip_bf16.h>
#include <math.h>

#define S_ 256
#define B_ 16
#define D_ 512
#define V_ 32000
#define L_ 4
#define DEC_ 0.6065306597126334f   // float(exp(-1/2))

typedef short v8s __attribute__((ext_vector_type(8)));
typedef float v4f __attribute__((ext_vector_type(4)));

static __device__ __forceinline__ short f2bf(float f){
  union { float f; unsigned u; } v; v.f = f;
  unsigned r = (v.u + 0x7FFFu + ((v.u >> 16) & 1u)) >> 16;  // RNE
  return (short)(unsigned short)r;
}

// ---------------- encoder GEMM + scratch zero-init + cvec (spare blocks) ----------------
// X[s*B+b][n] = emb[ids[b][s]] . enc_W[n][:] + enc_b[n]
// grid (65, 8): bm<64 = gemm tiles; bm==64,bn<4 = cvec for layer j=bn.
// cvec lives here (not in k_scansim) so the kernel boundary orders it before k_sim's reads.
__global__ __launch_bounds__(256) void k_gemm_enc(const int* __restrict__ ids,
                                                  const float* __restrict__ emb,
                                                  const float* __restrict__ encW,
                                                  const float* __restrict__ encb,
                                                  float* __restrict__ X,
                                                  unsigned* __restrict__ counts,
                                                  float* __restrict__ accum,
                                                  const float* __restrict__ inf_W,
                                                  const float* __restrict__ inf_b,
                                                  const float* __restrict__ err_b,
                                                  float* __restrict__ cvec){
  const int t = threadIdx.x;
  const int bm = blockIdx.x, bn = blockIdx.y;
  if (bm == 64){
    // cvec: c_j = err_b[j] @ inf_W[j]^T + inf_b[j]   (used by sim top-down)
    if (bn >= 4) return;
    int j = bn;
    #pragma unroll
    for (int h = 0; h < 2; ++h){
      int dp = t + h*256;
      const float* row = inf_W + ((size_t)j * D_ + dp) * D_;
      const float* eb = err_b + j * D_;
      float acc = inf_b[j * D_ + dp];
      for (int d = 0; d < D_; d += 8){
        float4 w0 = *(const float4*)(row + d);
        float4 w1 = *(const float4*)(row + d + 4);
        float4 e0 = *(const float4*)(eb + d);
        float4 e1 = *(const float4*)(eb + d + 4);
        acc += e0.x*w0.x + e0.y*w0.y + e0.z*w0.z + e0.w*w0.w;
        acc += e1.x*w1.x + e1.y*w1.y + e1.z*w1.z + e1.w*w1.w;
      }
      cvec[j * D_ + dp] = acc;
    }
    return;
  }
  __shared__ __align__(16) short As[64*40];
  __shared__ __align__(16) short Bs[64*40];
  __shared__ int ids_s[64];
  // zero-init scratch (k_scansim runs after this kernel completes)
  if (bn == 0 && bm < 16){
    int g = bm*256 + t;
    counts[g] = 0u;
    if (g < 2) accum[g] = 0.0f;
  }
  if (t < 64){
    int mg = bm*64 + t;
    int s = mg >> 4, b = mg & 15;       // row r = s*B + b
    ids_s[t] = ids[b * S_ + s];
  }
  __syncthreads();
  const int arow = t >> 2;
  const int kc = (t & 3) * 8;
  const int wave = t >> 6;
  const int l = t & 63;
  const int lm = l & 15;
  const int q = l >> 4;
  v4f acc[4] = {};
  for (int k0 = 0; k0 < D_; k0 += 32){
    const float* asrc = emb + (size_t)ids_s[arow] * D_ + k0 + kc;
    float4 a0 = *(const float4*)asrc;
    float4 a1 = *(const float4*)(asrc + 4);
    const float* bsrc = encW + (size_t)(bn*64 + arow) * D_ + k0 + kc;
    float4 b0 = *(const float4*)bsrc;
    float4 b1 = *(const float4*)(bsrc + 4);
    v8s av, bv;
    av[0]=f2bf(a0.x); av[1]=f2bf(a0.y); av[2]=f2bf(a0.z); av[3]=f2bf(a0.w);
    av[4]=f2bf(a1.x); av[5]=f2bf(a1.y); av[6]=f2bf(a1.z); av[7]=f2bf(a1.w);
    bv[0]=f2bf(b0.x); bv[1]=f2bf(b0.y); bv[2]=f2bf(b0.z); bv[3]=f2bf(b0.w);
    bv[4]=f2bf(b1.x); bv[5]=f2bf(b1.y); bv[6]=f2bf(b1.z); bv[7]=f2bf(b1.w);
    *(v8s*)&As[arow*40 + kc] = av;
    *(v8s*)&Bs[arow*40 + kc] = bv;
    __syncthreads();
    v8s af = *(const v8s*)&As[(wave*16 + lm)*40 + q*8];
    #pragma unroll
    for (int n = 0; n < 4; ++n){
      v8s bf = *(const v8s*)&Bs[(n*16 + lm)*40 + q*8];
      acc[n] = __builtin_amdgcn_mfma_f32_16x16x32_bf16(af, bf, acc[n], 0, 0, 0);
    }
    __syncthreads();
  }
  // C/D layout: col = lane&15, row = (lane>>4)*4 + reg  [m89/m91 verified]
  #pragma unroll
  for (int n = 0; n < 4; ++n){
    #pragma unroll
    for (int i = 0; i < 4; ++i){
      int mloc = wave*16 + q*4 + i;
      int nloc = n*16 + lm;
      int r  = bm*64 + mloc;
      int nn = bn*64 + nloc;
      X[(size_t)r * D_ + nn] = acc[n][i] + encb[nn];
    }
  }
}

// ---------------- merged encoder-LIF scan + recurrent sim: block b = batch b ----------------
__device__ __forceinline__ float wave_sum64(float x){
  #pragma unroll
  for (int o = 32; o > 0; o >>= 1) x += __shfl_xor(x, o);
  return x;
}

// block-wide matvec: thread tid owns output dim tid; input value v is dim tid of x.
__device__ __forceinline__ float blk_matvec(const float* __restrict__ W,
                                            const float* __restrict__ bias,
                                            float v, float* __restrict__ xs){
  __syncthreads();                 // previous consumers of xs are done
  xs[threadIdx.x] = v;
  __syncthreads();
  const float* row = W + (size_t)threadIdx.x * D_;
  float acc = bias[threadIdx.x];
  for (int d = 0; d < D_; d += 4){
    float4 w = *(const float4*)(row + d);
    acc += xs[d]*w.x + xs[d+1]*w.y + xs[d+2]*w.z + xs[d+3]*w.w;
  }
  return acc;
}

// block-wide LayerNorm over 512 values (one per thread).
__device__ __forceinline__ float blk_ln(float e, const float* __restrict__ g,
                                        const float* __restrict__ bb,
                                        float* __restrict__ red){
  const int tid = threadIdx.x, wid = tid >> 6, lane = tid & 63;
  float s = wave_sum64(e);
  __syncthreads();
  if (lane == 0) red[wid] = s;
  __syncthreads();
  float tot = 0.f;
  #pragma unroll
  for (int w = 0; w < 8; ++w) tot += red[w];
  float m = tot * (1.0f/512.0f);
  float dv = e - m;
  float s2 = wave_sum64(dv*dv);
  __syncthreads();
  if (lane == 0) red[wid] = s2;
  __syncthreads();
  float var = 0.f;
  #pragma unroll
  for (int w = 0; w < 8; ++w) var += red[w];
  var *= (1.0f/512.0f);
  float inv = 1.0f / sqrtf(var + 1e-5f);
  return dv * inv * g[tid] + bb[tid];
}

__global__ __launch_bounds__(512) void k_scansim(
    const float* __restrict__ X,
    const float* __restrict__ gen_W, const float* __restrict__ gen_b,
    const float* __restrict__ inf_W, const float* __restrict__ inf_b,
    const float* __restrict__ err_g, const float* __restrict__ err_b,
    const float* __restrict__ st_g, const float* __restrict__ st_b,
    const float* __restrict__ cvec,
    unsigned char* __restrict__ bu8,
    unsigned* __restrict__ counts, unsigned short* __restrict__ idxb,
    float* __restrict__ accum)
{
  const int b = blockIdx.x;           // 0..15
  const int tid = threadIdx.x;        // 0..511  (= dim)
  const int lane = tid & 63, wid = tid >> 6;
  __shared__ float xs[D_];
  __shared__ float red[8];
  __shared__ unsigned bunz_s[S_];
  __shared__ unsigned scnt;
  __shared__ unsigned flagw[8];

  // ---------- phase 1: encoder LIF scan for batch b (thread = dim) ----------
  #pragma unroll
  for (int i = 0; i < S_/512 + 1; ++i){
    int s = tid + i*512;
    if (s < S_) bunz_s[s] = 0u;
  }
  __syncthreads();
  {
    int g = b * D_ + tid;
    float mem = 0.0f;
    for (int s0 = 0; s0 < S_; s0 += 8){
      float x[8];
      #pragma unroll
      for (int i = 0; i < 8; ++i) x[i] = X[(size_t)(s0 + i) * (B_*D_) + g];
      #pragma unroll
      for (int i = 0; i < 8; ++i){
        mem = mem * DEC_ + x[i];
        float sp = (mem >= 1.0f) ? 1.0f : 0.0f;   // atan_spike(mem - 1) == (mem >= 1)
        mem *= (1.0f - sp);
        bu8[(size_t)(s0 + i) * (B_*D_) + g] = (unsigned char)sp;
        if (__any(sp != 0.0f)){ if (lane == 0) atomicOr(&bunz_s[s0 + i], 1u); }
      }
    }
  }

  // ---------- bias-zero vote (enables the zero-fixed-point skip) ----------
  bool okz = true;
  #pragma unroll
  for (int j = 0; j < 4; ++j){
    int d = j*D_ + tid;
    okz = okz && (gen_b[d]==0.f) && (inf_b[d]==0.f) && (err_b[d]==0.f) && (st_b[d]==0.f);
  }
  unsigned long long vote = __ballot(okz);
  if (lane == 0) flagw[wid] = (vote == ~0ull) ? 1u : 0u;
  __syncthreads();
  unsigned allz = 1u;
  #pragma unroll
  for (int w = 0; w < 8; ++w) allz &= flagw[w];
  const bool bias_zero = (allz != 0u);

  // ---------- phase 2: recurrent sim (block-wide, 1 dim/thread) ----------
  float st[4], gm[4], im[4];
  #pragma unroll
  for (int j = 0; j < 4; ++j){ st[j]=0.f; gm[j]=0.f; im[j]=0.f; }
  bool state_zero = true;
  float spk_acc = 0.f, memp_acc = 0.f;

  for (int t = 0; t < S_; ++t){
    bool nz = (bunz_s[t] != 0u);   // block-uniform
    if (state_zero && bias_zero && !nz) continue;   // zero fixed point: step identity, td_t = 0
    state_zero = false;

    float bu_v = (float)bu8[(size_t)(t*B_ + b)*D_ + tid];

    // ---- bottom-up ----
    #pragma unroll
    for (int j = 0; j < 4; ++j){
      float y = blk_matvec(gen_W + (size_t)j*D_*D_, gen_b + j*D_, st[j], xs);
      gm[j] = gm[j]*DEC_ + y;
      float pred = (gm[j] >= 1.0f) ? 1.0f : 0.0f;
      gm[j] *= (1.0f - pred);
      float e = bu_v - pred; e = e > 0.f ? e : 0.f;
      float eo = blk_ln(e, err_g + j*D_, err_b + j*D_, red);
      spk_acc += eo;
      float y2 = blk_matvec(inf_W + (size_t)j*D_*D_, inf_b + j*D_, eo, xs);
      im[j] = im[j]*DEC_ + y2;
      float su = (im[j] >= 1.0f) ? 1.0f : 0.0f;
      im[j] *= (1.0f - su);
      memp_acc += fabsf(im[j]);
      st[j] = blk_ln(st[j] + su, st_g + j*D_, st_b + j*D_, red);
      bu_v = st[j] > 0.f ? st[j] : 0.f;
    }

    // ---- top-down (err == LN(0) == err_b identically, so inf input is cvec[j]) ----
    float td = st[3];
    #pragma unroll
    for (int j = 3; j >= 0; --j){
      float y = blk_matvec(gen_W + (size_t)j*D_*D_, gen_b + j*D_, td, xs);
      gm[j] = gm[j]*DEC_ + y;
      float p = (gm[j] >= 1.0f) ? 1.0f : 0.0f;
      gm[j] *= (1.0f - p);
      td = p;
      float c = cvec[j*D_ + tid];
      im[j] = im[j]*DEC_ + c;
      float ss = (im[j] >= 1.0f) ? 1.0f : 0.0f;
      im[j] *= (1.0f - ss);
    }

    // ---- emit spike indices of final td (binary) ----
    if (tid == 0) scnt = 0u;
    __syncthreads();
    unsigned base = (unsigned)(t*B_ + b) * D_;
    if (td != 0.f){
      unsigned pos = atomicAdd(&scnt, 1u);
      idxb[base + pos] = (unsigned short)tid;
    }
    __syncthreads();
    if (tid == 0) counts[t*B_ + b] = scnt;
  }

  // ---------- scalar reductions ----------
  float s1 = wave_sum64(spk_acc);
  float s2 = wave_sum64(memp_acc);
  __syncthreads();
  if (lane == 0){ red[wid] = s1; flagw[wid] = __float_as_uint(s2); }
  __syncthreads();
  if (tid == 0){
    float a0 = 0.f, a1 = 0.f;
    #pragma unroll
    for (int w = 0; w < 8; ++w){ a0 += red[w]; a1 += __uint_as_float(flagw[w]); }
    atomicAdd(&accum[0], a0);
    atomicAdd(&accum[1], a1);
  }
}

// ---------------- logits: column-chunk-resident out_b, nontemporal row stream ----------------
// grid = 25 col-chunks x 128 row-groups; block = 1 wave (64 threads).
__global__ __launch_bounds__(64) void k_logits(const unsigned* __restrict__ counts,
                                               const unsigned short* __restrict__ idxb,
                                               const float* __restrict__ outW,
                                               const float* __restrict__ outb,
                                               const float* __restrict__ accum,
                                               float* __restrict__ out){
  const int chunk = blockIdx.x % 25;
  const int rg = blockIdx.x / 25;
  const int lane = threadIdx.x;
  if (blockIdx.x == 0 && lane == 0){
    const float inv = 1.0f / (float)(B_ * D_ * S_);   // mean over (B,D), then /S
    out[(size_t)B_ * S_ * V_ + 0] = accum[0] * inv;
    out[(size_t)B_ * S_ * V_ + 1] = accum[1] * inv;
  }
  const int colbase = chunk * 1280;
  v4f pay[5];
  #pragma unroll
  for (int k = 0; k < 5; ++k)
    pay[k] = *(const v4f*)(outb + colbase + k*256 + lane*4);

  // prefetch this block's 32 row-counts (lane r holds count for row rg*32+r)
  int prow = rg*32 + (lane & 31);
  unsigned myc = counts[(prow & 255) * B_ + (prow >> 8)];

  for (int r = 0; r < 32; ++r){
    int row = rg*32 + r;                      // row = b*S + s (output order)
    unsigned cnt = (unsigned)__shfl((int)myc, r);
    float* dst = out + (size_t)row * V_ + colbase;
    if (cnt == 0){
      #pragma unroll
      for (int k = 0; k < 5; ++k)
        __builtin_nontemporal_store(pay[k], (v4f*)(dst + k*256 + lane*4));
    } else {
      int s = row & 255, b = row >> 8;
      unsigned base = (unsigned)(s * B_ + b) * D_;
      v4f acc[5];
      #pragma unroll
      for (int k = 0; k < 5; ++k) acc[k] = pay[k];
      for (unsigned i = 0; i < cnt; ++i){
        int d = idxb[base + i];
        #pragma unroll
        for (int k = 0; k < 5; ++k){
          int v = colbase + k*256 + lane*4;
          acc[k].x += outW[(size_t)(v+0)*D_ + d];
          acc[k].y += outW[(size_t)(v+1)*D_ + d];
          acc[k].z += outW[(size_t)(v+2)*D_ + d];
          acc[k].w += outW[(size_t)(v+3)*D_ + d];
        }
      }
      #pragma unroll
      for (int k = 0; k < 5; ++k)
        __builtin_nontemporal_store(acc[k], (v4f*)(dst + k*256 + lane*4));
    }
  }
}

extern "C" void kernel_launch(void* const* d_in, const int* in_sizes, int n_in,
                              void* d_out, int out_size, void* d_ws, size_t ws_size,
                              hipStream_t stream){
  (void)in_sizes; (void)n_in; (void)out_size; (void)ws_size;
  const int*   input_ids = (const int*)d_in[0];
  const float* embedding = (const float*)d_in[1];
  const float* enc_W = (const float*)d_in[2];
  const float* enc_b = (const float*)d_in[3];
  const float* gen_W = (const float*)d_in[4];
  const float* gen_b = (const float*)d_in[5];
  const float* inf_W = (const float*)d_in[6];
  const float* inf_b = (const float*)d_in[7];
  const float* err_g = (const float*)d_in[8];
  const float* err_b = (const float*)d_in[9];
  const float* st_g  = (const float*)d_in[10];
  const float* st_b  = (const float*)d_in[11];
  const float* out_W = (const float*)d_in[12];
  const float* out_b = (const float*)d_in[13];
  float* out = (float*)d_out;
  char* ws = (char*)d_ws;

  float*          X      = (float*)(ws + 0);                 // 4096*512*4 = 8388608
  unsigned char*  bu     = (unsigned char*)(ws + 8388608);   // 4096*512   = 2097152
  unsigned short* idxb   = (unsigned short*)(ws + 10485760); // 4096*512*2 = 4194304
  unsigned*       counts = (unsigned*)(ws + 14680064);       // 4096*4
  float*          cvec   = (float*)(ws + 14712832);          // 4*512*4
  float*          accum  = (float*)(ws + 14721024);          // 2*4

  hipLaunchKernelGGL(k_gemm_enc, dim3(65, 8), dim3(256), 0, stream,
                     input_ids, embedding, enc_W, enc_b, X, counts, accum,
                     inf_W, inf_b, err_b, cvec);
  hipLaunchKernelGGL(k_scansim, dim3(16), dim3(512), 0, stream,
                     X, gen_W, gen_b, inf_W, inf_b, err_g, err_b, st_g, st_b,
                     cvec, bu, counts, idxb, accum);
  hipLaunchKernelGGL(k_logits, dim3(3200), dim3(64), 0, stream,
                     counts, idxb, out_W, out_b, accum, out);
}